// Round 1
// baseline (1525.815 us; speedup 1.0000x reference)
//
#include <hip/hip_runtime.h>
#include <math.h>

// Problem constants
#define BB 2
#define TT 1024
#define DD 1536
#define HH 12
#define DKk 64
#define DVv 128
#define TQK 768
#define TVv 1536
#define CQKV 3072   // 768 q + 768 k + 1536 v
#define EPSF 1e-6f

__device__ __forceinline__ float siluf(float x) { return x / (1.f + expf(-x)); }

// ---------------------------------------------------------------------------
// Tiled f32 GEMM: C[m][n] = sum_k X[m*Kd+k] * W[n*Kd+k]   (C = X @ W^T)
// X: (M,Kd) row-major, W: (N,Kd) row-major, C row stride ldc.
// BM=BN=128, BK=32, 256 threads, 8x8 per thread. Requires M%128==0, N%128==0,
// Kd%32==0 (true for all uses here).
// ---------------------------------------------------------------------------
__global__ __launch_bounds__(256) void gemm_xt(
    const float* __restrict__ X, const float* __restrict__ W,
    float* __restrict__ C, int M, int N, int Kd, int ldc)
{
  __shared__ float As[32][132];   // [k][row], pad 132 keeps 16B alignment of rows
  __shared__ float Bs[32][132];   // [k][col]
  const int tid = threadIdx.x;
  const int tx = tid & 15, ty = tid >> 4;
  const int rowA0 = blockIdx.y * 128;
  const int colB0 = blockIdx.x * 128;

  float acc[8][8];
#pragma unroll
  for (int i = 0; i < 8; ++i)
#pragma unroll
    for (int j = 0; j < 8; ++j) acc[i][j] = 0.f;

  for (int k0 = 0; k0 < Kd; k0 += 32) {
#pragma unroll
    for (int p = 0; p < 4; ++p) {
      int id = tid + p * 256;       // 0..1023
      int r = id >> 3;              // 0..127 (tile row/col)
      int kq = id & 7;              // float4 index within 32-wide k slab
      const float4 av = *(const float4*)(X + (size_t)(rowA0 + r) * Kd + k0 + kq * 4);
      const float4 bv = *(const float4*)(W + (size_t)(colB0 + r) * Kd + k0 + kq * 4);
      As[kq*4+0][r] = av.x; As[kq*4+1][r] = av.y; As[kq*4+2][r] = av.z; As[kq*4+3][r] = av.w;
      Bs[kq*4+0][r] = bv.x; Bs[kq*4+1][r] = bv.y; Bs[kq*4+2][r] = bv.z; Bs[kq*4+3][r] = bv.w;
    }
    __syncthreads();
#pragma unroll
    for (int kk = 0; kk < 32; ++kk) {
      float a[8], b[8];
#pragma unroll
      for (int i = 0; i < 8; ++i) a[i] = As[kk][ty*8+i];
#pragma unroll
      for (int j = 0; j < 8; ++j) b[j] = Bs[kk][tx*8+j];
#pragma unroll
      for (int i = 0; i < 8; ++i)
#pragma unroll
        for (int j = 0; j < 8; ++j) acc[i][j] = fmaf(a[i], b[j], acc[i][j]);
    }
    __syncthreads();
  }

#pragma unroll
  for (int i = 0; i < 8; ++i) {
    float* cp = C + (size_t)(rowA0 + ty*8 + i) * ldc + colB0 + tx*8;
    *(float4*)(cp)     = make_float4(acc[i][0], acc[i][1], acc[i][2], acc[i][3]);
    *(float4*)(cp + 4) = make_float4(acc[i][4], acc[i][5], acc[i][6], acc[i][7]);
  }
}

// ---------------------------------------------------------------------------
// Causal depthwise conv (K=4, left pad 3) + SiLU.
// pre: (B,T,3072) = [q768 | k768 | v1536]; writes transposed:
// qc,kc: (B,H,T,64)   vc: (B,H,T,128)
// ---------------------------------------------------------------------------
__global__ void conv_silu_kernel(
    const float* __restrict__ pre,
    const float* __restrict__ qw, const float* __restrict__ kw, const float* __restrict__ vw,
    float* __restrict__ qc, float* __restrict__ kc, float* __restrict__ vc)
{
  int idx = blockIdx.x * blockDim.x + threadIdx.x;
  if (idx >= BB*TT*CQKV) return;
  int c  = idx % CQKV;
  int bt = idx / CQKV;
  int t  = bt % TT;
  int b  = bt / TT;

  const float* wp;
  if (c < TQK)            wp = qw + (size_t)c * 4;
  else if (c < 2*TQK)     wp = kw + (size_t)(c - TQK) * 4;
  else                    wp = vw + (size_t)(c - 2*TQK) * 4;

  float s = 0.f;
#pragma unroll
  for (int j = 0; j < 4; ++j) {
    int ts = t - 3 + j;
    if (ts >= 0) s = fmaf(pre[(size_t)(b*TT + ts) * CQKV + c], wp[j], s);
  }
  s = siluf(s);

  if (c < TQK) {
    int h = c >> 6, d = c & 63;
    qc[((size_t)(b*HH + h) * TT + t) * 64 + d] = s;
  } else if (c < 2*TQK) {
    int c2 = c - TQK; int h = c2 >> 6, d = c2 & 63;
    kc[((size_t)(b*HH + h) * TT + t) * 64 + d] = s;
  } else {
    int c2 = c - 2*TQK; int h = c2 >> 7, d = c2 & 127;
    vc[((size_t)(b*HH + h) * TT + t) * 128 + d] = s;
  }
}

// ---------------------------------------------------------------------------
// In-place L2 normalize rows of 64 (q and k heads). One wave per row.
// ---------------------------------------------------------------------------
__global__ void l2norm64_kernel(float* __restrict__ buf, int nrows)
{
  int gid  = blockIdx.x * blockDim.x + threadIdx.x;
  int row  = gid >> 6;
  int lane = threadIdx.x & 63;
  if (row >= nrows) return;
  float v = buf[(size_t)row * 64 + lane];
  float ss = v * v;
#pragma unroll
  for (int m = 32; m >= 1; m >>= 1) ss += __shfl_xor(ss, m, 64);
  float n = sqrtf(ss);
  buf[(size_t)row * 64 + lane] = v / fmaxf(n, EPSF);
}

// ---------------------------------------------------------------------------
// Gating: one wave per (b,t,h): dota = x.w_a[h], dotb = x.w_b[h];
// alpha = exp(-exp(A_log)*softplus(dota+dt_bias)); beta = 2*sigmoid(dotb).
// Stored time-major (B,H,T).
// ---------------------------------------------------------------------------
__global__ void gate_kernel(
    const float* __restrict__ x, const float* __restrict__ w_a, const float* __restrict__ w_b,
    const float* __restrict__ A_log, const float* __restrict__ dt_bias,
    float* __restrict__ alpha, float* __restrict__ beta)
{
  int gid  = blockIdx.x * blockDim.x + threadIdx.x;
  int wid  = gid >> 6;
  int lane = threadIdx.x & 63;
  if (wid >= BB*TT*HH) return;
  int h = wid % HH;
  int m = wid / HH;            // m = b*T + t
  const float* xr = x   + (size_t)m * DD;
  const float* wa = w_a + (size_t)h * DD;
  const float* wb = w_b + (size_t)h * DD;
  float sa = 0.f, sb = 0.f;
  for (int i = lane; i < DD; i += 64) {
    float xv = xr[i];
    sa = fmaf(xv, wa[i], sa);
    sb = fmaf(xv, wb[i], sb);
  }
#pragma unroll
  for (int mm = 32; mm >= 1; mm >>= 1) {
    sa += __shfl_xor(sa, mm, 64);
    sb += __shfl_xor(sb, mm, 64);
  }
  if (lane == 0) {
    float a  = sa + dt_bias[h];
    float sp = (a > 20.f) ? a : log1pf(expf(a));
    float g  = -expf(A_log[h]) * sp;
    int b = m / TT, t = m % TT;
    size_t idx = (size_t)(b*HH + h) * TT + t;
    alpha[idx] = expf(g);
    beta[idx]  = 2.f / (1.f + expf(-sb));
  }
}

// ---------------------------------------------------------------------------
// Gated delta rule scan. State columns S[:,v] are independent: 96 blocks =
// (B*H) x 4 v-blocks of 32 columns; 256 threads = 32 cols x 8 lanes, each lane
// owns 8 of the 64 d's. No LDS, shuffles only within 8-lane groups.
// o written as (B,T,H,128).
// ---------------------------------------------------------------------------
__global__ __launch_bounds__(256) void scan_kernel(
    const float* __restrict__ qc, const float* __restrict__ kc, const float* __restrict__ vc,
    const float* __restrict__ alpha, const float* __restrict__ beta,
    float* __restrict__ o)
{
  const int blk  = blockIdx.x;
  const int vblk = blk & 3;       // 0..3
  const int bh   = blk >> 2;      // 0..23
  const int b    = bh / HH, h = bh % HH;
  const int tid  = threadIdx.x;
  const int vl   = tid >> 3;      // 0..31
  const int s    = tid & 7;       // 0..7
  const int v    = vblk * 32 + vl;
  const int d0   = s * 8;

  const float* kp = kc + (size_t)bh * TT * 64 + d0;
  const float* qp = qc + (size_t)bh * TT * 64 + d0;
  const float* vp = vc + (size_t)bh * TT * 128 + v;
  const float* ap = alpha + (size_t)bh * TT;
  const float* bp = beta  + (size_t)bh * TT;
  float* op = o + ((size_t)b * TT * HH + h) * 128 + v;

  float S[8];
#pragma unroll
  for (int i = 0; i < 8; ++i) S[i] = 0.f;

  for (int t = 0; t < TT; ++t) {
    const float4 k0 = *(const float4*)(kp);
    const float4 k1 = *(const float4*)(kp + 4);
    const float4 q0 = *(const float4*)(qp);
    const float4 q1 = *(const float4*)(qp + 4);
    const float vt = *vp;
    const float al = ap[t], be = bp[t];
    float kr[8] = {k0.x,k0.y,k0.z,k0.w,k1.x,k1.y,k1.z,k1.w};
    float qr[8] = {q0.x,q0.y,q0.z,q0.w,q1.x,q1.y,q1.z,q1.w};

    // kS_v = sum_d k[d]*S[d][v]
    float part = 0.f;
#pragma unroll
    for (int i = 0; i < 8; ++i) part = fmaf(kr[i], S[i], part);
    part += __shfl_xor(part, 1, 64);
    part += __shfl_xor(part, 2, 64);
    part += __shfl_xor(part, 4, 64);

    // S' = alpha*S + k * (v_t - alpha*beta*kS)
    const float c = vt - al * be * part;
    float opart = 0.f;
#pragma unroll
    for (int i = 0; i < 8; ++i) {
      S[i] = fmaf(al, S[i], c * kr[i]);
      opart = fmaf(S[i], qr[i], opart);
    }
    opart += __shfl_xor(opart, 1, 64);
    opart += __shfl_xor(opart, 2, 64);
    opart += __shfl_xor(opart, 4, 64);
    if (s == 0) *op = opart;

    kp += 64; qp += 64; vp += 128; op += HH * 128;
  }
}

// ---------------------------------------------------------------------------
// RMS norm over Dv=128 (no weight) then SiLU gate. One wave per (b,t,h),
// 2 elems/lane. go laid out (B,T,1536) for the output GEMM.
// ---------------------------------------------------------------------------
__global__ void rmsgate_kernel(const float* __restrict__ o, const float* __restrict__ gpre,
                               float* __restrict__ go)
{
  int gid  = blockIdx.x * blockDim.x + threadIdx.x;
  int wid  = gid >> 6;
  int lane = threadIdx.x & 63;
  if (wid >= BB*TT*HH) return;
  int h = wid % HH;
  int m = wid / HH;
  const float* orow = o + (size_t)wid * 128;
  float2 ov = *(const float2*)(orow + lane * 2);
  float ss = ov.x*ov.x + ov.y*ov.y;
#pragma unroll
  for (int mm = 32; mm >= 1; mm >>= 1) ss += __shfl_xor(ss, mm, 64);
  float scale = rsqrtf(ss * (1.f/128.f) + EPSF);
  const float* gr = gpre + (size_t)m * TVv + h * 128 + lane * 2;
  float g0 = gr[0], g1 = gr[1];
  float2 out;
  out.x = ov.x * scale * siluf(g0);
  out.y = ov.y * scale * siluf(g1);
  *(float2*)(go + (size_t)m * TVv + h * 128 + lane * 2) = out;
}

// ---------------------------------------------------------------------------
extern "C" void kernel_launch(void* const* d_in, const int* in_sizes, int n_in,
                              void* d_out, int out_size, void* d_ws, size_t ws_size,
                              hipStream_t stream) {
  (void)in_sizes; (void)n_in; (void)out_size; (void)ws_size;
  const float* x       = (const float*)d_in[0];
  const float* w_q     = (const float*)d_in[1];
  const float* w_k     = (const float*)d_in[2];
  const float* w_v     = (const float*)d_in[3];
  const float* w_a     = (const float*)d_in[4];
  const float* w_b     = (const float*)d_in[5];
  const float* w_g     = (const float*)d_in[6];
  const float* w_out   = (const float*)d_in[7];
  const float* A_log   = (const float*)d_in[8];
  const float* dt_bias = (const float*)d_in[9];
  const float* qcw     = (const float*)d_in[10];
  const float* kcw     = (const float*)d_in[11];
  const float* vcw     = (const float*)d_in[12];

  // Workspace layout (floats). Peak 63.1 MB.
  const size_t SZ_QKV = (size_t)BB*TT*CQKV;  // 6291456
  const size_t SZ_GP  = (size_t)BB*TT*TVv;   // 3145728
  const size_t SZ_QC  = (size_t)BB*HH*TT*64; // 1572864
  const size_t SZ_VC  = (size_t)BB*HH*TT*128;// 3145728
  const size_t SZ_AB  = (size_t)BB*HH*TT;    // 24576

  float* ws      = (float*)d_ws;
  float* qkv_pre = ws;
  float* g_pre   = qkv_pre + SZ_QKV;
  float* qc      = g_pre + SZ_GP;
  float* kc      = qc + SZ_QC;
  float* vc      = kc + SZ_QC;
  float* alphab  = vc + SZ_VC;
  float* betab   = alphab + SZ_AB;
  // o and go reuse qkv_pre (dead after conv); 2*SZ_GP == SZ_QKV exactly.
  float* o  = qkv_pre;
  float* go = qkv_pre + SZ_GP;

  const int M = BB*TT;  // 2048
  dim3 blk(256);

  // Projections
  gemm_xt<<<dim3(TQK/128, M/128), blk, 0, stream>>>(x, w_q, qkv_pre + 0,     M, TQK, DD, CQKV);
  gemm_xt<<<dim3(TQK/128, M/128), blk, 0, stream>>>(x, w_k, qkv_pre + TQK,   M, TQK, DD, CQKV);
  gemm_xt<<<dim3(TVv/128, M/128), blk, 0, stream>>>(x, w_v, qkv_pre + 2*TQK, M, TVv, DD, CQKV);
  gemm_xt<<<dim3(TVv/128, M/128), blk, 0, stream>>>(x, w_g, g_pre,           M, TVv, DD, TVv);

  // Gating coefficients (time-major)
  gate_kernel<<<(BB*TT*HH*64)/256, blk, 0, stream>>>(x, w_a, w_b, A_log, dt_bias, alphab, betab);

  // Causal depthwise conv + SiLU (writes transposed q/k/v)
  conv_silu_kernel<<<(BB*TT*CQKV + 255)/256, blk, 0, stream>>>(qkv_pre, qcw, kcw, vcw, qc, kc, vc);

  // L2 normalize q,k per head
  l2norm64_kernel<<<(BB*HH*TT*64)/256, blk, 0, stream>>>(qc, BB*HH*TT);
  l2norm64_kernel<<<(BB*HH*TT*64)/256, blk, 0, stream>>>(kc, BB*HH*TT);

  // Sequential gated delta scan
  scan_kernel<<<BB*HH*4, blk, 0, stream>>>(qc, kc, vc, alphab, betab, o);

  // RMS norm + SiLU gate
  rmsgate_kernel<<<(BB*TT*HH*64)/256, blk, 0, stream>>>(o, g_pre, go);

  // Output projection
  gemm_xt<<<dim3(TVv/128, M/128), blk, 0, stream>>>(go, w_out, (float*)d_out, M, TVv, DD, TVv);
}

// Round 3
// 659.289 us; speedup vs baseline: 2.3143x; 2.3143x over previous
//
#include <hip/hip_runtime.h>
#include <math.h>

#define BB 2
#define TT 1024
#define DD 1536
#define HH 12
#define TQK 768
#define TVv 1536
#define CQKV 3072
#define EPSF 1e-6f
#define TSC 32   // scan time-tile

typedef __attribute__((ext_vector_type(8))) short short8v;
typedef __attribute__((ext_vector_type(4))) float f32x4;

__device__ __forceinline__ float siluf(float x) { return x / (1.f + expf(-x)); }

__device__ __forceinline__ ushort f2b(float f) {
  union { float f; uint u; } a; a.f = f;
  uint u = a.u;
  uint r = (u + 0x7fffu + ((u >> 16) & 1u)) >> 16;   // round-to-nearest-even
  return (ushort)r;
}
__device__ __forceinline__ float b2f(ushort h) {
  union { uint u; float f; } a; a.u = (uint)h << 16; return a.f;
}

// ---------------------------------------------------------------------------
// Split-bf16 MFMA GEMM: C = X @ W^T with X ~ Xh+Xl, W ~ Wh+Wl (bf16 pairs).
// acc += Xl*Wh + Xh*Wl + Xh*Wh  (lo*lo dropped, ~2^-18 relative error).
// 128x128 tile, BK=64, 256 thr = 4 waves (2x2), wave = 64x64 = 4x4 frags of
// mfma_f32_16x16x32_bf16. LDS row stride 72 ushorts. M%128==N%128==0, K%64==0.
// ---------------------------------------------------------------------------
__global__ __launch_bounds__(256) void gemm_bf16s(
    const ushort* __restrict__ Xh, const ushort* __restrict__ Xl,
    const ushort* __restrict__ Wh, const ushort* __restrict__ Wl,
    float* __restrict__ C, int M, int N, int K, int ldc)
{
  __shared__ ushort Ah[128 * 72];
  __shared__ ushort Al[128 * 72];
  __shared__ ushort Bh[128 * 72];
  __shared__ ushort Bl[128 * 72];
  const int tid  = threadIdx.x;
  const int lane = tid & 63;
  const int wid  = tid >> 6;
  const int wr   = wid >> 1, wc = wid & 1;
  const int r0   = blockIdx.y * 128, c0 = blockIdx.x * 128;

  f32x4 acc[4][4];
#pragma unroll
  for (int m = 0; m < 4; ++m)
#pragma unroll
    for (int n = 0; n < 4; ++n)
#pragma unroll
      for (int j = 0; j < 4; ++j) acc[m][n][j] = 0.f;

  for (int k0 = 0; k0 < K; k0 += 64) {
#pragma unroll
    for (int p = 0; p < 4; ++p) {
      int id  = tid + p * 256;       // 0..1023
      int row = id >> 3;             // 0..127
      int kc8 = id & 7;              // 16B chunk in 64-wide k slab
      size_t xo = (size_t)(r0 + row) * K + k0 + kc8 * 8;
      size_t wo = (size_t)(c0 + row) * K + k0 + kc8 * 8;
      *(f32x4*)(Ah + row * 72 + kc8 * 8) = *(const f32x4*)(Xh + xo);
      *(f32x4*)(Al + row * 72 + kc8 * 8) = *(const f32x4*)(Xl + xo);
      *(f32x4*)(Bh + row * 72 + kc8 * 8) = *(const f32x4*)(Wh + wo);
      *(f32x4*)(Bl + row * 72 + kc8 * 8) = *(const f32x4*)(Wl + wo);
    }
    __syncthreads();
#pragma unroll
    for (int kk = 0; kk < 2; ++kk) {
      const int koff = kk * 32 + (lane >> 4) * 8;
      short8v ah[4], al_[4], bh[4], bl[4];
#pragma unroll
      for (int m = 0; m < 4; ++m) {
        const int ro = (wr * 64 + m * 16 + (lane & 15)) * 72 + koff;
        ah[m]  = *(const short8v*)(Ah + ro);
        al_[m] = *(const short8v*)(Al + ro);
      }
#pragma unroll
      for (int n = 0; n < 4; ++n) {
        const int ro = (wc * 64 + n * 16 + (lane & 15)) * 72 + koff;
        bh[n] = *(const short8v*)(Bh + ro);
        bl[n] = *(const short8v*)(Bl + ro);
      }
#pragma unroll
      for (int m = 0; m < 4; ++m)
#pragma unroll
        for (int n = 0; n < 4; ++n) {
          acc[m][n] = __builtin_amdgcn_mfma_f32_16x16x32_bf16(al_[m], bh[n], acc[m][n], 0, 0, 0);
          acc[m][n] = __builtin_amdgcn_mfma_f32_16x16x32_bf16(ah[m], bl[n], acc[m][n], 0, 0, 0);
          acc[m][n] = __builtin_amdgcn_mfma_f32_16x16x32_bf16(ah[m], bh[n], acc[m][n], 0, 0, 0);
        }
    }
    __syncthreads();
  }

  const int crow = (lane >> 4) * 4;
  const int ccol = lane & 15;
#pragma unroll
  for (int m = 0; m < 4; ++m)
#pragma unroll
    for (int j = 0; j < 4; ++j) {
      float* cp = C + (size_t)(r0 + wr * 64 + m * 16 + crow + j) * ldc + c0 + wc * 64 + ccol;
#pragma unroll
      for (int n = 0; n < 4; ++n) cp[n * 16] = acc[m][n][j];
    }
}

// ---------------------------------------------------------------------------
// f32 -> (bf16 hi, bf16 lo) split cast, 8 elems/thread, exact grid.
// ---------------------------------------------------------------------------
__global__ void cast_pair_kernel(const float* __restrict__ src,
                                 ushort* __restrict__ hi, ushort* __restrict__ lo)
{
  int cid = blockIdx.x * blockDim.x + threadIdx.x;
  size_t e = (size_t)cid * 8;
  float f[8];
  *(float4*)(f)     = *(const float4*)(src + e);
  *(float4*)(f + 4) = *(const float4*)(src + e + 4);
  ushort h[8], l[8];
#pragma unroll
  for (int j = 0; j < 8; ++j) {
    h[j] = f2b(f[j]);
    l[j] = f2b(f[j] - b2f(h[j]));
  }
  uint4 ph, pl;
  ph.x = (uint)h[0] | ((uint)h[1] << 16); ph.y = (uint)h[2] | ((uint)h[3] << 16);
  ph.z = (uint)h[4] | ((uint)h[5] << 16); ph.w = (uint)h[6] | ((uint)h[7] << 16);
  pl.x = (uint)l[0] | ((uint)l[1] << 16); pl.y = (uint)l[2] | ((uint)l[3] << 16);
  pl.z = (uint)l[4] | ((uint)l[5] << 16); pl.w = (uint)l[6] | ((uint)l[7] << 16);
  *(uint4*)(hi + e) = ph;
  *(uint4*)(lo + e) = pl;
}

// ---------------------------------------------------------------------------
// Causal depthwise conv (K=4) + SiLU; writes q/k/v transposed to (B,H,T,D).
// ---------------------------------------------------------------------------
__global__ void conv_silu_kernel(
    const float* __restrict__ pre,
    const float* __restrict__ qw, const float* __restrict__ kw, const float* __restrict__ vw,
    float* __restrict__ qc, float* __restrict__ kc, float* __restrict__ vc)
{
  int idx = blockIdx.x * blockDim.x + threadIdx.x;
  if (idx >= BB * TT * CQKV) return;
  int c  = idx % CQKV;
  int bt = idx / CQKV;
  int t  = bt % TT;
  int b  = bt / TT;

  const float* wp;
  if (c < TQK)          wp = qw + (size_t)c * 4;
  else if (c < 2 * TQK) wp = kw + (size_t)(c - TQK) * 4;
  else                  wp = vw + (size_t)(c - 2 * TQK) * 4;

  float s = 0.f;
#pragma unroll
  for (int j = 0; j < 4; ++j) {
    int ts = t - 3 + j;
    if (ts >= 0) s = fmaf(pre[(size_t)(b * TT + ts) * CQKV + c], wp[j], s);
  }
  s = siluf(s);

  if (c < TQK) {
    int h = c >> 6, d = c & 63;
    qc[((size_t)(b * HH + h) * TT + t) * 64 + d] = s;
  } else if (c < 2 * TQK) {
    int c2 = c - TQK; int h = c2 >> 6, d = c2 & 63;
    kc[((size_t)(b * HH + h) * TT + t) * 64 + d] = s;
  } else {
    int c2 = c - 2 * TQK; int h = c2 >> 7, d = c2 & 127;
    vc[((size_t)(b * HH + h) * TT + t) * 128 + d] = s;
  }
}

__global__ void l2norm64_kernel(float* __restrict__ buf, int nrows)
{
  int gid  = blockIdx.x * blockDim.x + threadIdx.x;
  int row  = gid >> 6;
  int lane = threadIdx.x & 63;
  if (row >= nrows) return;
  float v = buf[(size_t)row * 64 + lane];
  float ss = v * v;
#pragma unroll
  for (int m = 32; m >= 1; m >>= 1) ss += __shfl_xor(ss, m, 64);
  float n = sqrtf(ss);
  buf[(size_t)row * 64 + lane] = v / fmaxf(n, EPSF);
}

__global__ void gate_kernel(
    const float* __restrict__ x, const float* __restrict__ w_a, const float* __restrict__ w_b,
    const float* __restrict__ A_log, const float* __restrict__ dt_bias,
    float* __restrict__ alpha, float* __restrict__ beta)
{
  int gid  = blockIdx.x * blockDim.x + threadIdx.x;
  int wid  = gid >> 6;
  int lane = threadIdx.x & 63;
  if (wid >= BB * TT * HH) return;
  int h = wid % HH;
  int m = wid / HH;
  const float* xr = x   + (size_t)m * DD;
  const float* wa = w_a + (size_t)h * DD;
  const float* wb = w_b + (size_t)h * DD;
  float sa = 0.f, sb = 0.f;
  for (int i = lane; i < DD; i += 64) {
    float xv = xr[i];
    sa = fmaf(xv, wa[i], sa);
    sb = fmaf(xv, wb[i], sb);
  }
#pragma unroll
  for (int mm = 32; mm >= 1; mm >>= 1) {
    sa += __shfl_xor(sa, mm, 64);
    sb += __shfl_xor(sb, mm, 64);
  }
  if (lane == 0) {
    float a  = sa + dt_bias[h];
    float sp = (a > 20.f) ? a : log1pf(expf(a));
    float g  = -expf(A_log[h]) * sp;
    int b = m / TT, t = m % TT;
    size_t idx = (size_t)(b * HH + h) * TT + t;
    alpha[idx] = expf(g);
    beta[idx]  = 2.f / (1.f + expf(-sb));
  }
}

// ---------------------------------------------------------------------------
// Gated delta scan, LDS-staged time tiles of TSC=32.
// 96 blocks = (B*H) x 4 vblocks of 32 columns; 256 thr = 32 cols x 8 lanes.
// Off-chain output: o = al*(q.S_old) + c*(q.k); only k.S reduce on the chain.
// ---------------------------------------------------------------------------
__global__ __launch_bounds__(256) void scan_kernel(
    const float* __restrict__ qc, const float* __restrict__ kc, const float* __restrict__ vc,
    const float* __restrict__ alpha, const float* __restrict__ beta,
    float* __restrict__ o)
{
  __shared__ float k_lds[TSC * 64];
  __shared__ float q_lds[TSC * 64];
  __shared__ float v_lds[TSC * 32];
  __shared__ float a_lds[TSC];
  __shared__ float b_lds[TSC];

  const int blk  = blockIdx.x;
  const int vblk = blk & 3;
  const int bh   = blk >> 2;
  const int b    = bh / HH, h = bh % HH;
  const int tid  = threadIdx.x;
  const int col  = tid >> 3;          // 0..31
  const int s    = tid & 7;           // 0..7, owns d = s*8..s*8+7
  const int v    = vblk * 32 + col;

  const float* kg = kc + (size_t)bh * TT * 64;
  const float* qg = qc + (size_t)bh * TT * 64;
  const float* vg = vc + (size_t)bh * TT * 128 + vblk * 32;
  const float* ag = alpha + (size_t)bh * TT;
  const float* bg = beta  + (size_t)bh * TT;
  float* op = o + ((size_t)b * TT * HH + h) * 128 + v;

  const int vrow = (tid * 4) >> 5;    // 0..31
  const int vcl  = (tid * 4) & 31;

  float S[8];
#pragma unroll
  for (int i = 0; i < 8; ++i) S[i] = 0.f;

  float4 rk0, rk1, rq0, rq1, rv; float rab;
#define LOADTILE(T0) do { \
    rk0 = *(const float4*)(kg + (size_t)(T0) * 64 + tid * 8); \
    rk1 = *(const float4*)(kg + (size_t)(T0) * 64 + tid * 8 + 4); \
    rq0 = *(const float4*)(qg + (size_t)(T0) * 64 + tid * 8); \
    rq1 = *(const float4*)(qg + (size_t)(T0) * 64 + tid * 8 + 4); \
    rv  = *(const float4*)(vg + (size_t)((T0) + vrow) * 128 + vcl); \
    rab = (tid < 32) ? ag[(T0) + tid] : ((tid < 64) ? bg[(T0) + tid - 32] : 0.f); \
  } while (0)

  LOADTILE(0);
  for (int tile = 0; tile < TT / TSC; ++tile) {
    __syncthreads();                       // prior tile's reads complete
    *(float4*)(k_lds + tid * 8)     = rk0;
    *(float4*)(k_lds + tid * 8 + 4) = rk1;
    *(float4*)(q_lds + tid * 8)     = rq0;
    *(float4*)(q_lds + tid * 8 + 4) = rq1;
    *(float4*)(v_lds + tid * 4)     = rv;
    if (tid < 32) a_lds[tid] = rab;
    else if (tid < 64) b_lds[tid - 32] = rab;
    if (tile + 1 < TT / TSC) LOADTILE((tile + 1) * TSC);  // in flight during compute
    __syncthreads();

#pragma unroll 4
    for (int i = 0; i < TSC; ++i) {
      const float4 kk0 = *(const float4*)(k_lds + i * 64 + s * 8);
      const float4 kk1 = *(const float4*)(k_lds + i * 64 + s * 8 + 4);
      const float4 qq0 = *(const float4*)(q_lds + i * 64 + s * 8);
      const float4 qq1 = *(const float4*)(q_lds + i * 64 + s * 8 + 4);
      const float vt = v_lds[i * 32 + col];
      const float al = a_lds[i], be = b_lds[i];
      const float kr[8] = {kk0.x, kk0.y, kk0.z, kk0.w, kk1.x, kk1.y, kk1.z, kk1.w};
      const float qr[8] = {qq0.x, qq0.y, qq0.z, qq0.w, qq1.x, qq1.y, qq1.z, qq1.w};

      float pa = kr[0] * S[0], pb = kr[4] * S[4];
      float sa = qr[0] * S[0], sb = qr[4] * S[4];
      float ta = qr[0] * kr[0], tb = qr[4] * kr[4];
#pragma unroll
      for (int j = 1; j < 4; ++j) {
        pa = fmaf(kr[j], S[j], pa);     pb = fmaf(kr[j + 4], S[j + 4], pb);
        sa = fmaf(qr[j], S[j], sa);     sb = fmaf(qr[j + 4], S[j + 4], sb);
        ta = fmaf(qr[j], kr[j], ta);    tb = fmaf(qr[j + 4], kr[j + 4], tb);
      }
      float part = pa + pb;   // k.S  (serial chain)
      float qs   = sa + sb;   // q.S  (off-chain)
      float qk   = ta + tb;   // q.k  (off-chain)
      part += __shfl_xor(part, 1); part += __shfl_xor(part, 2); part += __shfl_xor(part, 4);
      qs   += __shfl_xor(qs, 1);   qs   += __shfl_xor(qs, 2);   qs   += __shfl_xor(qs, 4);
      qk   += __shfl_xor(qk, 1);   qk   += __shfl_xor(qk, 2);   qk   += __shfl_xor(qk, 4);
      const float c = fmaf(-al * be, part, vt);
#pragma unroll
      for (int j = 0; j < 8; ++j) S[j] = fmaf(al, S[j], c * kr[j]);
      if (s == 0) *op = fmaf(al, qs, c * qk);
      op += HH * 128;
    }
  }
#undef LOADTILE
}

// ---------------------------------------------------------------------------
// RMS norm over 128 + SiLU gate; emits split bf16 (hi+lo) for final GEMM.
// ---------------------------------------------------------------------------
__global__ void rmsgate_kernel(const float* __restrict__ o, const float* __restrict__ gpre,
                               ushort* __restrict__ goh, ushort* __restrict__ gol)
{
  int gid  = blockIdx.x * blockDim.x + threadIdx.x;
  int wid  = gid >> 6;
  int lane = threadIdx.x & 63;
  if (wid >= BB * TT * HH) return;
  int h = wid % HH;
  int m = wid / HH;
  const float* orow = o + (size_t)wid * 128;
  float2 ov = *(const float2*)(orow + lane * 2);
  float ss = ov.x * ov.x + ov.y * ov.y;
#pragma unroll
  for (int mm = 32; mm >= 1; mm >>= 1) ss += __shfl_xor(ss, mm, 64);
  float scale = rsqrtf(ss * (1.f / 128.f) + EPSF);
  const float* gr = gpre + (size_t)m * TVv + h * 128 + lane * 2;
  float o0 = ov.x * scale * siluf(gr[0]);
  float o1 = ov.y * scale * siluf(gr[1]);
  ushort h0 = f2b(o0), h1 = f2b(o1);
  ushort l0 = f2b(o0 - b2f(h0)), l1 = f2b(o1 - b2f(h1));
  size_t idx = (size_t)m * TVv + h * 128 + lane * 2;
  *(uint*)(goh + idx) = (uint)h0 | ((uint)h1 << 16);
  *(uint*)(gol + idx) = (uint)l0 | ((uint)l1 << 16);
}

// ---------------------------------------------------------------------------
extern "C" void kernel_launch(void* const* d_in, const int* in_sizes, int n_in,
                              void* d_out, int out_size, void* d_ws, size_t ws_size,
                              hipStream_t stream) {
  (void)in_sizes; (void)n_in; (void)out_size; (void)ws_size;
  const float* x       = (const float*)d_in[0];
  const float* w_q     = (const float*)d_in[1];
  const float* w_k     = (const float*)d_in[2];
  const float* w_v     = (const float*)d_in[3];
  const float* w_a     = (const float*)d_in[4];
  const float* w_b     = (const float*)d_in[5];
  const float* w_g     = (const float*)d_in[6];
  const float* w_out   = (const float*)d_in[7];
  const float* A_log   = (const float*)d_in[8];
  const float* dt_bias = (const float*)d_in[9];
  const float* qcw     = (const float*)d_in[10];
  const float* kcw     = (const float*)d_in[11];
  const float* vcw     = (const float*)d_in[12];

  // Workspace (63.11 MB, same as validated round-1 footprint):
  //  A [0 .. 6291456)        qkv_pre f32; later o[0..3145728) + goh/gol (bf16)
  //  B [6291456 .. 9437184)  g_pre f32
  //  C [9437184 .. 15728640) phase1: xh,xl + per-GEMM weight hi/lo scratch
  //                          phase2: qc,kc,vc
  //                          phase3: wout hi/lo
  //  [15728640 .. 15777792)  alpha, beta
  float* ws      = (float*)d_ws;
  float* qkv_pre = ws;
  float* g_pre   = ws + 6291456;
  float* Cu      = ws + 9437184;
  float* alphab  = ws + 15728640;
  float* betab   = ws + 15753216;

  ushort* xh = (ushort*)Cu;                    // 3,145,728 ushorts
  ushort* xl = (ushort*)(Cu + 1572864);
  ushort* wh = (ushort*)(Cu + 3145728);        // up to 2,359,296 ushorts
  ushort* wl = (ushort*)(Cu + 4325376);

  float* qc = Cu;
  float* kc = Cu + 1572864;
  float* vc = Cu + 3145728;

  ushort* wouth = (ushort*)Cu;                 // 2,359,296 ushorts
  ushort* woutl = (ushort*)(Cu + 1179648);

  float*  o   = qkv_pre;
  ushort* goh = (ushort*)(qkv_pre + 3145728);
  ushort* gol = (ushort*)(qkv_pre + 4718592);

  const int M = BB * TT;  // 2048
  dim3 blk(256);

  // 1) split-cast x, then per-weight JIT cast + projection GEMM
  cast_pair_kernel<<<1536, blk, 0, stream>>>(x, xh, xl);

  cast_pair_kernel<<<576, blk, 0, stream>>>(w_q, wh, wl);
  gemm_bf16s<<<dim3(TQK / 128, M / 128), blk, 0, stream>>>(xh, xl, wh, wl, qkv_pre + 0,       M, TQK, DD, CQKV);
  cast_pair_kernel<<<576, blk, 0, stream>>>(w_k, wh, wl);
  gemm_bf16s<<<dim3(TQK / 128, M / 128), blk, 0, stream>>>(xh, xl, wh, wl, qkv_pre + TQK,     M, TQK, DD, CQKV);
  cast_pair_kernel<<<1152, blk, 0, stream>>>(w_v, wh, wl);
  gemm_bf16s<<<dim3(TVv / 128, M / 128), blk, 0, stream>>>(xh, xl, wh, wl, qkv_pre + 2 * TQK, M, TVv, DD, CQKV);
  cast_pair_kernel<<<1152, blk, 0, stream>>>(w_g, wh, wl);
  gemm_bf16s<<<dim3(TVv / 128, M / 128), blk, 0, stream>>>(xh, xl, wh, wl, g_pre,             M, TVv, DD, TVv);

  // 2) gating coefficients (f32, exact)
  gate_kernel<<<6144, blk, 0, stream>>>(x, w_a, w_b, A_log, dt_bias, alphab, betab);

  // 3) causal depthwise conv + SiLU (overwrites xh/xl/wh/wl with qc/kc/vc)
  conv_silu_kernel<<<(BB * TT * CQKV + 255) / 256, blk, 0, stream>>>(qkv_pre, qcw, kcw, vcw, qc, kc, vc);

  // 4) L2 normalize q,k
  l2norm64_kernel<<<6144, blk, 0, stream>>>(qc, BB * HH * TT);
  l2norm64_kernel<<<6144, blk, 0, stream>>>(kc, BB * HH * TT);

  // 5) scan
  scan_kernel<<<BB * HH * 4, blk, 0, stream>>>(qc, kc, vc, alphab, betab, o);

  // 6) split-cast w_out into freed qc/kc space
  cast_pair_kernel<<<1152, blk, 0, stream>>>(w_out, wouth, woutl);

  // 7) RMS norm + SiLU gate -> split bf16
  rmsgate_kernel<<<6144, blk, 0, stream>>>(o, g_pre, goh, gol);

  // 8) output projection
  gemm_bf16s<<<dim3(TVv / 128, M / 128), blk, 0, stream>>>(goh, gol, wouth, woutl, (float*)d_out, M, TVv, DD, TVv);
}

// Round 4
// 466.196 us; speedup vs baseline: 3.2729x; 1.4142x over previous
//
#include <hip/hip_runtime.h>
#include <math.h>

#define BB 2
#define TT 1024
#define DD 1536
#define HH 12
#define TQK 768
#define TVv 1536
#define CQKV 3072
#define EPSF 1e-6f
#define TSC 32   // scan time-tile

typedef __attribute__((ext_vector_type(8))) short short8v;
typedef __attribute__((ext_vector_type(4))) float f32x4;

__device__ __forceinline__ float siluf(float x) { return x / (1.f + expf(-x)); }

__device__ __forceinline__ ushort f2b(float f) {
  union { float f; uint u; } a; a.f = f;
  uint u = a.u;
  uint r = (u + 0x7fffu + ((u >> 16) & 1u)) >> 16;   // round-to-nearest-even
  return (ushort)r;
}
__device__ __forceinline__ float b2f(ushort h) {
  union { uint u; float f; } a; a.u = (uint)h << 16; return a.f;
}

// DPP add: x += lane-permuted x. Pure VALU (no DS pipe, no lgkmcnt).
// 0xB1 = quad_perm[1,0,3,2] (xor1), 0x4E = quad_perm[2,3,0,1] (xor2),
// 0x141 = row_half_mirror (swap quads within each 8-lane group).
template <int CTRL>
__device__ __forceinline__ float dpp_xadd(float x) {
  union { float f; int i; } a, b;
  a.f = x;
  b.i = __builtin_amdgcn_update_dpp(0, a.i, CTRL, 0xF, 0xF, true);
  return x + b.f;
}
__device__ __forceinline__ float red8_dpp(float x) {
  x = dpp_xadd<0xB1>(x);
  x = dpp_xadd<0x4E>(x);
  x = dpp_xadd<0x141>(x);
  return x;
}

// ---------------------------------------------------------------------------
// Split-bf16 MFMA GEMM: C = X @ W^T with X ~ Xh+Xl, W ~ Wh+Wl (bf16 pairs).
// acc += Xl*Wh + Xh*Wl + Xh*Wh. 128x128 tile, BK=64, 4 waves, 4x4 frags of
// mfma_f32_16x16x32_bf16. LDS row stride 72 ushorts.
// ---------------------------------------------------------------------------
__global__ __launch_bounds__(256) void gemm_bf16s(
    const ushort* __restrict__ Xh, const ushort* __restrict__ Xl,
    const ushort* __restrict__ Wh, const ushort* __restrict__ Wl,
    float* __restrict__ C, int M, int N, int K, int ldc)
{
  __shared__ ushort Ah[128 * 72];
  __shared__ ushort Al[128 * 72];
  __shared__ ushort Bh[128 * 72];
  __shared__ ushort Bl[128 * 72];
  const int tid  = threadIdx.x;
  const int lane = tid & 63;
  const int wid  = tid >> 6;
  const int wr   = wid >> 1, wc = wid & 1;
  const int r0   = blockIdx.y * 128, c0 = blockIdx.x * 128;

  f32x4 acc[4][4];
#pragma unroll
  for (int m = 0; m < 4; ++m)
#pragma unroll
    for (int n = 0; n < 4; ++n)
#pragma unroll
      for (int j = 0; j < 4; ++j) acc[m][n][j] = 0.f;

  for (int k0 = 0; k0 < K; k0 += 64) {
#pragma unroll
    for (int p = 0; p < 4; ++p) {
      int id  = tid + p * 256;
      int row = id >> 3;
      int kc8 = id & 7;
      size_t xo = (size_t)(r0 + row) * K + k0 + kc8 * 8;
      size_t wo = (size_t)(c0 + row) * K + k0 + kc8 * 8;
      *(f32x4*)(Ah + row * 72 + kc8 * 8) = *(const f32x4*)(Xh + xo);
      *(f32x4*)(Al + row * 72 + kc8 * 8) = *(const f32x4*)(Xl + xo);
      *(f32x4*)(Bh + row * 72 + kc8 * 8) = *(const f32x4*)(Wh + wo);
      *(f32x4*)(Bl + row * 72 + kc8 * 8) = *(const f32x4*)(Wl + wo);
    }
    __syncthreads();
#pragma unroll
    for (int kk = 0; kk < 2; ++kk) {
      const int koff = kk * 32 + (lane >> 4) * 8;
      short8v ah[4], al_[4], bh[4], bl[4];
#pragma unroll
      for (int m = 0; m < 4; ++m) {
        const int ro = (wr * 64 + m * 16 + (lane & 15)) * 72 + koff;
        ah[m]  = *(const short8v*)(Ah + ro);
        al_[m] = *(const short8v*)(Al + ro);
      }
#pragma unroll
      for (int n = 0; n < 4; ++n) {
        const int ro = (wc * 64 + n * 16 + (lane & 15)) * 72 + koff;
        bh[n] = *(const short8v*)(Bh + ro);
        bl[n] = *(const short8v*)(Bl + ro);
      }
#pragma unroll
      for (int m = 0; m < 4; ++m)
#pragma unroll
        for (int n = 0; n < 4; ++n) {
          acc[m][n] = __builtin_amdgcn_mfma_f32_16x16x32_bf16(al_[m], bh[n], acc[m][n], 0, 0, 0);
          acc[m][n] = __builtin_amdgcn_mfma_f32_16x16x32_bf16(ah[m], bl[n], acc[m][n], 0, 0, 0);
          acc[m][n] = __builtin_amdgcn_mfma_f32_16x16x32_bf16(ah[m], bh[n], acc[m][n], 0, 0, 0);
        }
    }
    __syncthreads();
  }

  const int crow = (lane >> 4) * 4;
  const int ccol = lane & 15;
#pragma unroll
  for (int m = 0; m < 4; ++m)
#pragma unroll
    for (int j = 0; j < 4; ++j) {
      float* cp = C + (size_t)(r0 + wr * 64 + m * 16 + crow + j) * ldc + c0 + wc * 64 + ccol;
#pragma unroll
      for (int n = 0; n < 4; ++n) cp[n * 16] = acc[m][n][j];
    }
}

// ---------------------------------------------------------------------------
// f32 -> (bf16 hi, bf16 lo) split cast, 8 elems/thread, exact grid.
// ---------------------------------------------------------------------------
__device__ __forceinline__ void split8_store(const float* f, ushort* hi, ushort* lo, size_t e)
{
  ushort h[8], l[8];
#pragma unroll
  for (int j = 0; j < 8; ++j) {
    h[j] = f2b(f[j]);
    l[j] = f2b(f[j] - b2f(h[j]));
  }
  uint4 ph, pl;
  ph.x = (uint)h[0] | ((uint)h[1] << 16); ph.y = (uint)h[2] | ((uint)h[3] << 16);
  ph.z = (uint)h[4] | ((uint)h[5] << 16); ph.w = (uint)h[6] | ((uint)h[7] << 16);
  pl.x = (uint)l[0] | ((uint)l[1] << 16); pl.y = (uint)l[2] | ((uint)l[3] << 16);
  pl.z = (uint)l[4] | ((uint)l[5] << 16); pl.w = (uint)l[6] | ((uint)l[7] << 16);
  *(uint4*)(hi + e) = ph;
  *(uint4*)(lo + e) = pl;
}

__global__ void cast_pair_kernel(const float* __restrict__ src,
                                 ushort* __restrict__ hi, ushort* __restrict__ lo)
{
  int cid = blockIdx.x * blockDim.x + threadIdx.x;
  size_t e = (size_t)cid * 8;
  float f[8];
  *(float4*)(f)     = *(const float4*)(src + e);
  *(float4*)(f + 4) = *(const float4*)(src + e + 4);
  split8_store(f, hi, lo, e);
}

// Concatenated q|k|v weight cast into (3072,1536) hi/lo.
__global__ void cast_qkv_kernel(const float* __restrict__ wq, const float* __restrict__ wk,
                                const float* __restrict__ wv,
                                ushort* __restrict__ hi, ushort* __restrict__ lo)
{
  int cid = blockIdx.x * blockDim.x + threadIdx.x;
  size_t e = (size_t)cid * 8;
  const float* src; size_t off;
  if (e < 1179648)      { src = wq; off = e; }
  else if (e < 2359296) { src = wk; off = e - 1179648; }
  else                  { src = wv; off = e - 2359296; }
  float f[8];
  *(float4*)(f)     = *(const float4*)(src + off);
  *(float4*)(f + 4) = *(const float4*)(src + off + 4);
  split8_store(f, hi, lo, e);
}

// ---------------------------------------------------------------------------
// Causal depthwise conv (K=4) + SiLU; writes q/k/v transposed to (B,H,T,D).
// ---------------------------------------------------------------------------
__global__ void conv_silu_kernel(
    const float* __restrict__ pre,
    const float* __restrict__ qw, const float* __restrict__ kw, const float* __restrict__ vw,
    float* __restrict__ qc, float* __restrict__ kc, float* __restrict__ vc)
{
  int idx = blockIdx.x * blockDim.x + threadIdx.x;
  if (idx >= BB * TT * CQKV) return;
  int c  = idx % CQKV;
  int bt = idx / CQKV;
  int t  = bt % TT;
  int b  = bt / TT;

  const float* wp;
  if (c < TQK)          wp = qw + (size_t)c * 4;
  else if (c < 2 * TQK) wp = kw + (size_t)(c - TQK) * 4;
  else                  wp = vw + (size_t)(c - 2 * TQK) * 4;

  float s = 0.f;
#pragma unroll
  for (int j = 0; j < 4; ++j) {
    int ts = t - 3 + j;
    if (ts >= 0) s = fmaf(pre[(size_t)(b * TT + ts) * CQKV + c], wp[j], s);
  }
  s = siluf(s);

  if (c < TQK) {
    int h = c >> 6, d = c & 63;
    qc[((size_t)(b * HH + h) * TT + t) * 64 + d] = s;
  } else if (c < 2 * TQK) {
    int c2 = c - TQK; int h = c2 >> 6, d = c2 & 63;
    kc[((size_t)(b * HH + h) * TT + t) * 64 + d] = s;
  } else {
    int c2 = c - 2 * TQK; int h = c2 >> 7, d = c2 & 127;
    vc[((size_t)(b * HH + h) * TT + t) * 128 + d] = s;
  }
}

__global__ void l2norm64_kernel(float* __restrict__ buf, int nrows)
{
  int gid  = blockIdx.x * blockDim.x + threadIdx.x;
  int row  = gid >> 6;
  int lane = threadIdx.x & 63;
  if (row >= nrows) return;
  float v = buf[(size_t)row * 64 + lane];
  float ss = v * v;
#pragma unroll
  for (int m = 32; m >= 1; m >>= 1) ss += __shfl_xor(ss, m, 64);
  float n = sqrtf(ss);
  buf[(size_t)row * 64 + lane] = v / fmaxf(n, EPSF);
}

// ---------------------------------------------------------------------------
// Gating: one block per row m; 4 waves x 6 outputs (12 a-dots + 12 b-dots).
// x row read once per wave; w_a/w_b stay L2-resident.
// ---------------------------------------------------------------------------
__global__ __launch_bounds__(256) void gate_kernel(
    const float* __restrict__ x, const float* __restrict__ w_a, const float* __restrict__ w_b,
    const float* __restrict__ A_log, const float* __restrict__ dt_bias,
    float* __restrict__ alpha, float* __restrict__ beta)
{
  const int m    = blockIdx.x;          // 0..2047
  const int w    = threadIdx.x >> 6;    // 0..3
  const int lane = threadIdx.x & 63;
  const float* xr = x + (size_t)m * DD;
  float xv[24];
#pragma unroll
  for (int i = 0; i < 24; ++i) xv[i] = xr[lane + i * 64];
  const int b = m / TT, t = m % TT;
#pragma unroll
  for (int j = 0; j < 6; ++j) {
    int o = w * 6 + j;                  // 0..23
    bool isA = o < HH;
    int h = isA ? o : o - HH;
    const float* wr = (isA ? w_a : w_b) + (size_t)h * DD;
    float s = 0.f;
#pragma unroll
    for (int i = 0; i < 24; ++i) s = fmaf(xv[i], wr[lane + i * 64], s);
#pragma unroll
    for (int mm = 32; mm >= 1; mm >>= 1) s += __shfl_xor(s, mm, 64);
    if (lane == 0) {
      size_t idx = (size_t)(b * HH + h) * TT + t;
      if (isA) {
        float a  = s + dt_bias[h];
        float sp = (a > 20.f) ? a : log1pf(expf(a));
        alpha[idx] = expf(-expf(A_log[h]) * sp);
      } else {
        beta[idx] = 2.f / (1.f + expf(-s));
      }
    }
  }
}

// ---------------------------------------------------------------------------
// Gated delta scan, LDS-staged time tiles; all reduces via DPP (no DS pipe
// on the serial chain). 96 blocks = (B*H) x 4 vblocks; 32 cols x 8 lanes.
// ---------------------------------------------------------------------------
__global__ __launch_bounds__(256) void scan_kernel(
    const float* __restrict__ qc, const float* __restrict__ kc, const float* __restrict__ vc,
    const float* __restrict__ alpha, const float* __restrict__ beta,
    float* __restrict__ o)
{
  __shared__ float k_lds[TSC * 64];
  __shared__ float q_lds[TSC * 64];
  __shared__ float v_lds[TSC * 32];
  __shared__ float a_lds[TSC];
  __shared__ float b_lds[TSC];

  const int blk  = blockIdx.x;
  const int vblk = blk & 3;
  const int bh   = blk >> 2;
  const int b    = bh / HH, h = bh % HH;
  const int tid  = threadIdx.x;
  const int col  = tid >> 3;          // 0..31
  const int s    = tid & 7;           // 0..7, owns d = s*8..s*8+7
  const int v    = vblk * 32 + col;

  const float* kg = kc + (size_t)bh * TT * 64;
  const float* qg = qc + (size_t)bh * TT * 64;
  const float* vg = vc + (size_t)bh * TT * 128 + vblk * 32;
  const float* ag = alpha + (size_t)bh * TT;
  const float* bg = beta  + (size_t)bh * TT;
  float* op = o + ((size_t)b * TT * HH + h) * 128 + v;

  const int vrow = (tid * 4) >> 5;
  const int vcl  = (tid * 4) & 31;

  float S[8];
#pragma unroll
  for (int i = 0; i < 8; ++i) S[i] = 0.f;

  float4 rk0, rk1, rq0, rq1, rv; float rab;
#define LOADTILE(T0) do { \
    rk0 = *(const float4*)(kg + (size_t)(T0) * 64 + tid * 8); \
    rk1 = *(const float4*)(kg + (size_t)(T0) * 64 + tid * 8 + 4); \
    rq0 = *(const float4*)(qg + (size_t)(T0) * 64 + tid * 8); \
    rq1 = *(const float4*)(qg + (size_t)(T0) * 64 + tid * 8 + 4); \
    rv  = *(const float4*)(vg + (size_t)((T0) + vrow) * 128 + vcl); \
    rab = (tid < 32) ? ag[(T0) + tid] : ((tid < 64) ? bg[(T0) + tid - 32] : 0.f); \
  } while (0)

  LOADTILE(0);
  for (int tile = 0; tile < TT / TSC; ++tile) {
    __syncthreads();
    *(float4*)(k_lds + tid * 8)     = rk0;
    *(float4*)(k_lds + tid * 8 + 4) = rk1;
    *(float4*)(q_lds + tid * 8)     = rq0;
    *(float4*)(q_lds + tid * 8 + 4) = rq1;
    *(float4*)(v_lds + tid * 4)     = rv;
    if (tid < 32) a_lds[tid] = rab;
    else if (tid < 64) b_lds[tid - 32] = rab;
    if (tile + 1 < TT / TSC) LOADTILE((tile + 1) * TSC);
    __syncthreads();

#pragma unroll 4
    for (int i = 0; i < TSC; ++i) {
      const float4 kk0 = *(const float4*)(k_lds + i * 64 + s * 8);
      const float4 kk1 = *(const float4*)(k_lds + i * 64 + s * 8 + 4);
      const float4 qq0 = *(const float4*)(q_lds + i * 64 + s * 8);
      const float4 qq1 = *(const float4*)(q_lds + i * 64 + s * 8 + 4);
      const float vt = v_lds[i * 32 + col];
      const float al = a_lds[i], be = b_lds[i];
      const float kr[8] = {kk0.x, kk0.y, kk0.z, kk0.w, kk1.x, kk1.y, kk1.z, kk1.w};
      const float qr[8] = {qq0.x, qq0.y, qq0.z, qq0.w, qq1.x, qq1.y, qq1.z, qq1.w};

      float pa = kr[0] * S[0], pb = kr[4] * S[4];
      float sa = qr[0] * S[0], sb = qr[4] * S[4];
      float ta = qr[0] * kr[0], tb = qr[4] * kr[4];
#pragma unroll
      for (int j = 1; j < 4; ++j) {
        pa = fmaf(kr[j], S[j], pa);     pb = fmaf(kr[j + 4], S[j + 4], pb);
        sa = fmaf(qr[j], S[j], sa);     sb = fmaf(qr[j + 4], S[j + 4], sb);
        ta = fmaf(qr[j], kr[j], ta);    tb = fmaf(qr[j + 4], kr[j + 4], tb);
      }
      float part = red8_dpp(pa + pb);   // k.S (serial chain, pure VALU now)
      float qs   = red8_dpp(sa + sb);   // q.S (off-chain)
      float qk   = red8_dpp(ta + tb);   // q.k (off-chain)
      const float c = fmaf(-al * be, part, vt);
#pragma unroll
      for (int j = 0; j < 8; ++j) S[j] = fmaf(al, S[j], c * kr[j]);
      if (s == 0) *op = fmaf(al, qs, c * qk);
      op += HH * 128;
    }
  }
#undef LOADTILE
}

// ---------------------------------------------------------------------------
// RMS norm over 128 + SiLU gate; emits split bf16 (hi+lo) for final GEMM.
// ---------------------------------------------------------------------------
__global__ void rmsgate_kernel(const float* __restrict__ o, const float* __restrict__ gpre,
                               ushort* __restrict__ goh, ushort* __restrict__ gol)
{
  int gid  = blockIdx.x * blockDim.x + threadIdx.x;
  int wid  = gid >> 6;
  int lane = threadIdx.x & 63;
  if (wid >= BB * TT * HH) return;
  int h = wid % HH;
  int m = wid / HH;
  const float* orow = o + (size_t)wid * 128;
  float2 ov = *(const float2*)(orow + lane * 2);
  float ss = ov.x * ov.x + ov.y * ov.y;
#pragma unroll
  for (int mm = 32; mm >= 1; mm >>= 1) ss += __shfl_xor(ss, mm, 64);
  float scale = rsqrtf(ss * (1.f / 128.f) + EPSF);
  const float* gr = gpre + (size_t)m * TVv + h * 128 + lane * 2;
  float o0 = ov.x * scale * siluf(gr[0]);
  float o1 = ov.y * scale * siluf(gr[1]);
  ushort h0 = f2b(o0), h1 = f2b(o1);
  ushort l0 = f2b(o0 - b2f(h0)), l1 = f2b(o1 - b2f(h1));
  size_t idx = (size_t)m * TVv + h * 128 + lane * 2;
  *(uint*)(goh + idx) = (uint)h0 | ((uint)h1 << 16);
  *(uint*)(gol + idx) = (uint)l0 | ((uint)l1 << 16);
}

// ---------------------------------------------------------------------------
extern "C" void kernel_launch(void* const* d_in, const int* in_sizes, int n_in,
                              void* d_out, int out_size, void* d_ws, size_t ws_size,
                              hipStream_t stream) {
  (void)in_sizes; (void)n_in; (void)out_size; (void)ws_size;
  const float* x       = (const float*)d_in[0];
  const float* w_q     = (const float*)d_in[1];
  const float* w_k     = (const float*)d_in[2];
  const float* w_v     = (const float*)d_in[3];
  const float* w_a     = (const float*)d_in[4];
  const float* w_b     = (const float*)d_in[5];
  const float* w_g     = (const float*)d_in[6];
  const float* w_out   = (const float*)d_in[7];
  const float* A_log   = (const float*)d_in[8];
  const float* dt_bias = (const float*)d_in[9];
  const float* qcw     = (const float*)d_in[10];
  const float* kcw     = (const float*)d_in[11];
  const float* vcw     = (const float*)d_in[12];

  // Workspace (63.11 MB, same proven footprint):
  //  qkv_pre [0 .. 6291456)      f32; later o[0..3145728) + goh/gol
  //  g_pre   [6291456 .. 9437184) f32; transiently holds wcat_hi before g GEMM
  //  Cu      [9437184 .. 15728640): phase1 xh,xl + wcat_lo / wg hi,lo
  //                                 phase2 qc,kc,vc ; phase3 wout hi,lo
  //  alpha/beta [15728640 .. 15777792)
  float* ws      = (float*)d_ws;
  float* qkv_pre = ws;
  float* g_pre   = ws + 6291456;
  float* Cu      = ws + 9437184;
  float* alphab  = ws + 15728640;
  float* betab   = ws + 15753216;

  ushort* xh    = (ushort*)Cu;                  // 3,145,728 ushorts
  ushort* xl    = (ushort*)(Cu + 1572864);
  ushort* wcath = (ushort*)g_pre;               // 4,718,592 ushorts (transient)
  ushort* wcatl = (ushort*)(Cu + 3145728);      // 4,718,592 ushorts
  ushort* wgh   = (ushort*)(Cu + 3145728);      // reuses wcatl space after qkv GEMM
  ushort* wgl   = (ushort*)(Cu + 4325376);

  float* qc = Cu;
  float* kc = Cu + 1572864;
  float* vc = Cu + 3145728;

  ushort* wouth = (ushort*)Cu;
  ushort* woutl = (ushort*)(Cu + 1179648);

  float*  o   = qkv_pre;
  ushort* goh = (ushort*)(qkv_pre + 3145728);
  ushort* gol = (ushort*)(qkv_pre + 4718592);

  const int M = BB * TT;  // 2048
  dim3 blk(256);

  // 1) split-casts: x, concatenated q|k|v weights
  cast_pair_kernel<<<1536, blk, 0, stream>>>(x, xh, xl);
  cast_qkv_kernel<<<2304, blk, 0, stream>>>(w_q, w_k, w_v, wcath, wcatl);

  // 2) fused qkv projection (N=3072)
  gemm_bf16s<<<dim3(CQKV / 128, M / 128), blk, 0, stream>>>(xh, xl, wcath, wcatl, qkv_pre, M, CQKV, DD, CQKV);

  // 3) g projection (wcat dead; wg overwrites wcatl, g_pre overwrites wcath)
  cast_pair_kernel<<<1152, blk, 0, stream>>>(w_g, wgh, wgl);
  gemm_bf16s<<<dim3(TVv / 128, M / 128), blk, 0, stream>>>(xh, xl, wgh, wgl, g_pre, M, TVv, DD, TVv);

  // 4) gating coefficients (f32, exact)
  gate_kernel<<<M, blk, 0, stream>>>(x, w_a, w_b, A_log, dt_bias, alphab, betab);

  // 5) causal depthwise conv + SiLU (overwrites Cu with qc/kc/vc)
  conv_silu_kernel<<<(BB * TT * CQKV + 255) / 256, blk, 0, stream>>>(qkv_pre, qcw, kcw, vcw, qc, kc, vc);

  // 6) L2 normalize q,k
  l2norm64_kernel<<<6144, blk, 0, stream>>>(qc, BB * HH * TT);
  l2norm64_kernel<<<6144, blk, 0, stream>>>(kc, BB * HH * TT);

  // 7) scan (DPP reduces)
  scan_kernel<<<BB * HH * 4, blk, 0, stream>>>(qc, kc, vc, alphab, betab, o);

  // 8) split-cast w_out into freed qc/kc space
  cast_pair_kernel<<<1152, blk, 0, stream>>>(w_out, wouth, woutl);

  // 9) RMS norm + SiLU gate -> split bf16
  rmsgate_kernel<<<6144, blk, 0, stream>>>(o, g_pre, goh, gol);

  // 10) output projection
  gemm_bf16s<<<dim3(TVv / 128, M / 128), blk, 0, stream>>>(goh, gol, wouth, woutl, (float*)d_out, M, TVv, DD, TVv);
}